// Round 8
// baseline (144.777 us; speedup 1.0000x reference)
//
#include <hip/hip_runtime.h>

#define NN 16384      // nodes
#define NE 65536      // edges
#define H  32
#define BB 32
#define NPERB 512

// ---- prep: embed (f4) + type-matrices (all layers) + int deg histogram ----
__global__ __launch_bounds__(256) void k_prep(
    const int* __restrict__ x_nodes, const int* __restrict__ edge_index,
    const float* __restrict__ node_emb, const float* __restrict__ edge_emb,
    const float* __restrict__ lin_w, const float* __restrict__ lin_b,
    float* __restrict__ x0, float* __restrict__ Wt, int* __restrict__ deg) {
    int b = blockIdx.x, thr = threadIdx.x;
    if (b < 512) {                          // embed: 131072 float4 tasks
        int t = b * 256 + thr;
        int n = t >> 3, r = t & 7;
        ((float4*)x0)[t] = ((const float4*)node_emb)[x_nodes[n] * 8 + r];
    } else if (b < 768) {                   // Wt: 65536 tasks (4 layers x 16 ty x 1024)
        int w = (b - 512) * 256 + thr;      // l*16384 + ty*1024 + io
        int l = w >> 14, rest = w & 16383;
        int ty = rest >> 10, io = rest & 1023;
        float acc = lin_b[l * 1024 + io];
#pragma unroll
        for (int jj = 0; jj < 8; ++jj) {
            float e2 = fmaxf(edge_emb[(l * 16 + ty) * 8 + jj], 0.f);
            acc = fmaf(e2, lin_w[(l * 8 + jj) * 1024 + io], acc);
        }
        Wt[w] = acc;
    } else {                                // deg histogram: 65536 edges
        int e = (b - 768) * 256 + thr;
        atomicAdd(&deg[edge_index[NE + e]], 1);
    }
}

// ---- exclusive scan of deg (16384 ints) in one block; offs[NN] = NE ----
__global__ void k_scan(const int* __restrict__ deg, int* __restrict__ offs) {
    __shared__ int sums[1024];
    int t = threadIdx.x;
    int v[16];
    int s = 0;
#pragma unroll
    for (int i = 0; i < 16; ++i) { v[i] = deg[t * 16 + i]; s += v[i]; }
    sums[t] = s;
    __syncthreads();
    for (int off = 1; off < 1024; off <<= 1) {
        int a = (t >= off) ? sums[t - off] : 0;
        __syncthreads();
        sums[t] += a;
        __syncthreads();
    }
    int run = (t > 0) ? sums[t - 1] : 0;
#pragma unroll
    for (int i = 0; i < 16; ++i) { offs[t * 16 + i] = run; run += v[i]; }
    if (t == 1023) offs[NN] = run;          // = NE
}

// ---- scatter edges into dst-sorted slots: slist[slot] = src | ty<<14 ----
__global__ __launch_bounds__(256) void k_scatter(
    const int* __restrict__ edge_index, const int* __restrict__ edge_attr,
    const int* __restrict__ offs, int* __restrict__ cnt,
    unsigned int* __restrict__ slist) {
    int e = blockIdx.x * 256 + threadIdx.x;
    int s = edge_index[e], d = edge_index[NE + e], ty = edge_attr[e];
    int slot = offs[d] + atomicAdd(&cnt[d], 1);
    slist[slot] = (unsigned int)s | ((unsigned int)ty << 14);
}

// ---- stage 1: per-edge messages, W in LDS, plain coalesced stores, no atomics ----
// 512 thr (16 lane-groups of 32), 64KB LDS, 512 blocks (2/CU), 8 edges per group.
__global__ __launch_bounds__(512, 4) void k_msg(
    const float* __restrict__ xin, const unsigned int* __restrict__ slist,
    const float* __restrict__ Wl, float* __restrict__ msg, int relu_in) {
    __shared__ float Ws[16384];             // all 16 type-matrices (64KB)
    int thr = threadIdx.x;
    {
        const float4* s4 = (const float4*)Wl;
        float4* d4 = (float4*)Ws;
#pragma unroll
        for (int k = 0; k < 8; ++k) d4[k * 512 + thr] = s4[k * 512 + thr];
    }
    __syncthreads();
    int g = blockIdx.x * 16 + (thr >> 5);   // group id 0..8191
    int o = thr & 31;
    int base = thr & 32;                    // half-wave base for shfl
    unsigned int p = slist[g];              // edge e = g (k=0), uniform per group
    float xv = xin[(p & 16383) * H + o];
#pragma unroll 1
    for (int k = 0; k < 8; ++k) {
        int e = k * 8192 + g;
        unsigned int p_next = 0; float xv_next = 0.f;
        if (k < 7) {                        // prefetch next edge + its x row
            p_next = slist[e + 8192];
            xv_next = xin[(p_next & 16383) * H + o];
        }
        int ty = (int)(p >> 14);
        float xr = relu_in ? fmaxf(xv, 0.f) : xv;
        const float* __restrict__ W = Ws + ty * 1024 + o;
        float acc = 0.f;
#pragma unroll
        for (int i = 0; i < 32; ++i)        // LDS: lane o -> bank o, conflict-free
            acc = fmaf(__shfl(xr, base + i), W[i * 32], acc);
        msg[e * H + o] = acc;               // coalesced plain store
        p = p_next; xv = xv_next;
    }
}

// ---- stage 2: per-node run-sum of msg + /deg + root matvec + bias, plain store ----
__global__ __launch_bounds__(256) void k_node(
    const float* __restrict__ xin, const float* __restrict__ msg,
    const int* __restrict__ offs, const float* __restrict__ Rl,
    const float* __restrict__ Bl, float* __restrict__ xout, int relu_in) {
    int t = blockIdx.x * 256 + threadIdx.x;
    int n = t >> 5, o = t & 31, base = threadIdx.x & 32;
    int e0 = offs[n], e1 = offs[n + 1];
    float acc = 0.f;
    int e = e0;
    for (; e + 4 <= e1; e += 4) {           // independent pipelined 128B loads
        float m0 = msg[(e + 0) * H + o], m1 = msg[(e + 1) * H + o];
        float m2 = msg[(e + 2) * H + o], m3 = msg[(e + 3) * H + o];
        acc += (m0 + m1) + (m2 + m3);
    }
    for (; e < e1; ++e) acc += msg[e * H + o];
    float invd = __builtin_amdgcn_rcpf(fmaxf((float)(e1 - e0), 1.f));
    float xv = xin[t];
    float xr = relu_in ? fmaxf(xv, 0.f) : xv;
    float r = Bl[o];
#pragma unroll
    for (int i = 0; i < 32; ++i)
        r = fmaf(__shfl(xr, base + i), Rl[i * 32 + o], r);
    xout[t] = acc * invd + r;
}

// ---- readout: one thread per output element (B x 128) ----
__global__ void k_final(const float* __restrict__ x, const int* __restrict__ metal_idx,
                        const int* __restrict__ loop_edge, const int* __restrict__ loop_pair,
                        const float* __restrict__ f_w, const float* __restrict__ f_b,
                        float* __restrict__ out) {
    int tid = blockIdx.x * blockDim.x + threadIdx.x;
    if (tid >= BB * 128) return;
    int b = tid >> 7, j = tid & 127;
    int mg = metal_idx[b] + b * NPERB;
    const float* __restrict__ xm = x + mg * H;
    int p0, p1;
    if (j < 64) {
        p0 = loop_edge[(b * 64 + j) * 2];
        p1 = loop_edge[(b * 64 + j) * 2 + 1];
    } else {
        int j2 = j - 64;
        p0 = loop_pair[(b * 64 + j2) * 2];
        p1 = loop_pair[(b * 64 + j2) * 2 + 1];
    }
    const float* __restrict__ xs = x + (b * NPERB + p0) * H;
    const float* __restrict__ xt = x + (b * NPERB + p1) * H;
    float fh = f_b[0];
    float pp = 0.f;
#pragma unroll
    for (int h = 0; h < H; ++h) {
        float m = xm[h];
        fh = fmaf(m, f_w[h], fh);
        pp += m * (xs[h] + xt[h]) - xs[h] * xt[h];
    }
    out[tid] = (j < 64) ? (pp - fh) : (-pp);
}

extern "C" void kernel_launch(void* const* d_in, const int* in_sizes, int n_in,
                              void* d_out, int out_size, void* d_ws, size_t ws_size,
                              hipStream_t stream) {
    const int*   x_nodes    = (const int*)d_in[0];
    const int*   edge_index = (const int*)d_in[1];
    const int*   edge_attr  = (const int*)d_in[2];
    const int*   metal_idx  = (const int*)d_in[3];
    const int*   loop_edge  = (const int*)d_in[4];
    const int*   loop_pair  = (const int*)d_in[5];
    const float* node_emb   = (const float*)d_in[6];
    const float* edge_emb   = (const float*)d_in[7];
    const float* lin_w      = (const float*)d_in[8];
    const float* lin_b      = (const float*)d_in[9];
    const float* root_w     = (const float*)d_in[10];
    const float* conv_b     = (const float*)d_in[11];
    const float* f_w        = (const float*)d_in[12];
    const float* f_b        = (const float*)d_in[13];
    float* out = (float*)d_out;

    float* ws   = (float*)d_ws;
    float* buf0 = ws;                          // NN*H
    float* buf1 = buf0 + NN * H;               // NN*H
    float* msg  = buf1 + NN * H;               // NE*H (8MB)
    int*   deg  = (int*)(msg + NE * H);        // NN  (zeroed)
    int*   cnt  = deg + NN;                    // NN  (zeroed, contiguous)
    int*   offs = cnt + NN;                    // NN+1
    unsigned int* slist = (unsigned int*)(offs + NN + 1);  // NE
    float* Wt   = (float*)(slist + NE);        // 4*16*1024

    hipMemsetAsync(deg, 0, 2 * NN * sizeof(int), stream);

    k_prep<<<1024, 256, 0, stream>>>(x_nodes, edge_index, node_emb, edge_emb,
                                     lin_w, lin_b, buf0, Wt, deg);
    k_scan<<<1, 1024, 0, stream>>>(deg, offs);
    k_scatter<<<256, 256, 0, stream>>>(edge_index, edge_attr, offs, cnt, slist);

    // l0: buf0 -> buf1 (relu_in 0); l1: buf1 -> buf0; l2: buf0 -> buf1; l3: buf1 -> buf0
    k_msg<<<512, 512, 0, stream>>>(buf0, slist, Wt + 0 * 16384, msg, 0);
    k_node<<<2048, 256, 0, stream>>>(buf0, msg, offs, root_w + 0 * 1024, conv_b + 0 * H, buf1, 0);
    k_msg<<<512, 512, 0, stream>>>(buf1, slist, Wt + 1 * 16384, msg, 1);
    k_node<<<2048, 256, 0, stream>>>(buf1, msg, offs, root_w + 1 * 1024, conv_b + 1 * H, buf0, 1);
    k_msg<<<512, 512, 0, stream>>>(buf0, slist, Wt + 2 * 16384, msg, 1);
    k_node<<<2048, 256, 0, stream>>>(buf0, msg, offs, root_w + 2 * 1024, conv_b + 2 * H, buf1, 1);
    k_msg<<<512, 512, 0, stream>>>(buf1, slist, Wt + 3 * 16384, msg, 1);
    k_node<<<2048, 256, 0, stream>>>(buf1, msg, offs, root_w + 3 * 1024, conv_b + 3 * H, buf0, 1);

    k_final<<<16, 256, 0, stream>>>(buf0, metal_idx, loop_edge, loop_pair, f_w, f_b, out);
}

// Round 9
// 97.688 us; speedup vs baseline: 1.4820x; 1.4820x over previous
//
#include <hip/hip_runtime.h>

#define NN 16384      // nodes
#define NE 65536      // edges
#define H  32
#define BB 32
#define NPERB 512

// ---- prep1: embed (f4) + type-matrices + deg hist + type hist + zero buf1 ----
__global__ __launch_bounds__(256) void k_prep1(
    const int* __restrict__ x_nodes, const int* __restrict__ edge_index,
    const int* __restrict__ edge_attr, const float* __restrict__ node_emb,
    const float* __restrict__ edge_emb, const float* __restrict__ lin_w,
    const float* __restrict__ lin_b, float* __restrict__ x0, float* __restrict__ Wt,
    float* __restrict__ degf, int* __restrict__ tcount, float* __restrict__ zb1) {
    __shared__ int lh[16];
    int b = blockIdx.x, thr = threadIdx.x;
    if (b < 512) {                          // embed: 131072 float4 tasks
        int t = b * 256 + thr;
        int n = t >> 3, r = t & 7;
        ((float4*)x0)[t] = ((const float4*)node_emb)[x_nodes[n] * 8 + r];
    } else if (b < 768) {                   // Wt: 65536 tasks (4 layers x 16 ty)
        int w = (b - 512) * 256 + thr;      // l*16384 + ty*1024 + io
        int l = w >> 14, rest = w & 16383;
        int ty = rest >> 10, io = rest & 1023;
        float acc = lin_b[l * 1024 + io];
#pragma unroll
        for (int jj = 0; jj < 8; ++jj) {
            float e2 = fmaxf(edge_emb[(l * 16 + ty) * 8 + jj], 0.f);
            acc = fmaf(e2, lin_w[(l * 8 + jj) * 1024 + io], acc);
        }
        Wt[w] = acc;
    } else if (b < 1024) {                  // edges: deg + type hist
        if (thr < 16) lh[thr] = 0;
        __syncthreads();
        int e = (b - 768) * 256 + thr;
        int d = edge_index[NE + e];
        int ty = edge_attr[e];
        atomicAdd(&degf[d], 1.0f);
        atomicAdd(&lh[ty], 1);
        __syncthreads();
        if (thr < 16) atomicAdd(&tcount[thr], lh[thr]);
    } else {                                // zero buf1: 131072 float4 tasks
        int z = (b - 1024) * 256 + thr;
        ((float4*)zb1)[z] = make_float4(0.f, 0.f, 0.f, 0.f);
    }
}

// ---- prep2: exclusive scan of 16 type counts -> bucket cursors ----
__global__ void k_prep2(const int* __restrict__ tcount, int* __restrict__ gcursor) {
    int t = threadIdx.x;
    int c = (t < 16) ? tcount[t] : 0;
    int base = 0;
    for (int u = 0; u < 15; ++u) {
        int cu = __shfl(c, u);
        if (u < t) base += cu;
    }
    if (t < 16) gcursor[t] = base;
}

// ---- prep3: counting-sort scatter into type buckets: blist[slot]=src|dst<<14|ty<<28 ----
__global__ __launch_bounds__(256) void k_prep3(
    const int* __restrict__ edge_index, const int* __restrict__ edge_attr,
    int* __restrict__ gcursor, unsigned int* __restrict__ blist) {
    __shared__ int lh[16], lb[16];
    int thr = threadIdx.x;
    if (thr < 16) lh[thr] = 0;
    __syncthreads();
    int e = blockIdx.x * 256 + thr;
    unsigned int s = (unsigned int)edge_index[e];
    unsigned int d = (unsigned int)edge_index[NE + e];
    int ty = edge_attr[e];
    int rank = atomicAdd(&lh[ty], 1);
    __syncthreads();
    if (thr < 16) lb[thr] = atomicAdd(&gcursor[thr], lh[thr]);
    __syncthreads();
    blist[lb[ty] + rank] = s | (d << 14) | ((unsigned int)ty << 28);
}

// ---- one layer, 4-way MLP edge tasks ----
// blocks [0,2048)    : 4 edges per thread (strided by 16384 edges)
// blocks [2048,3072) : 2 self tasks per thread
// blocks [3072,4096) : 2 zero tasks per thread (skipped when zb==0)
#define EBLK 2048
#define SBLK 1024
__global__ __launch_bounds__(256) void k_phase(
    const float* __restrict__ xin, float* __restrict__ xout, float* __restrict__ zb,
    const unsigned int* __restrict__ blist, const float* __restrict__ degf,
    const float* __restrict__ Wl, const float* __restrict__ Rl,
    const float* __restrict__ Bl, int relu_in) {
    int b = blockIdx.x;
    int base = threadIdx.x & 32;            // half-wave base for shfl broadcast
    if (b < EBLK) {
        int t = b * 256 + threadIdx.x;      // 524288 threads
        int o = t & 31;
        int eg = t >> 5;                    // 16384 edge-groups per chunk
        // 4 independent edges: issue all index loads, then all x-row loads
        unsigned int p0 = blist[eg];
        unsigned int p1 = blist[eg + 16384];
        unsigned int p2 = blist[eg + 32768];
        unsigned int p3 = blist[eg + 49152];
        float x0 = xin[(p0 & 16383) * H + o];
        float x1 = xin[(p1 & 16383) * H + o];
        float x2 = xin[(p2 & 16383) * H + o];
        float x3 = xin[(p3 & 16383) * H + o];
        if (relu_in) {
            x0 = fmaxf(x0, 0.f); x1 = fmaxf(x1, 0.f);
            x2 = fmaxf(x2, 0.f); x3 = fmaxf(x3, 0.f);
        }
        int d0 = (p0 >> 14) & 16383, d1 = (p1 >> 14) & 16383;
        int d2 = (p2 >> 14) & 16383, d3 = (p3 >> 14) & 16383;
        float i0 = __builtin_amdgcn_rcpf(fmaxf(degf[d0], 1.0f));
        float i1 = __builtin_amdgcn_rcpf(fmaxf(degf[d1], 1.0f));
        float i2 = __builtin_amdgcn_rcpf(fmaxf(degf[d2], 1.0f));
        float i3 = __builtin_amdgcn_rcpf(fmaxf(degf[d3], 1.0f));
        const float* __restrict__ W0 = Wl + (p0 >> 28) * 1024 + o;
        const float* __restrict__ W1 = Wl + (p1 >> 28) * 1024 + o;
        const float* __restrict__ W2 = Wl + (p2 >> 28) * 1024 + o;
        const float* __restrict__ W3 = Wl + (p3 >> 28) * 1024 + o;
        float a0 = 0.f, a1 = 0.f, a2 = 0.f, a3 = 0.f;
#pragma unroll
        for (int i = 0; i < 32; ++i) {      // 4 interleaved independent chains
            a0 = fmaf(__shfl(x0, base + i), W0[i * 32], a0);
            a1 = fmaf(__shfl(x1, base + i), W1[i * 32], a1);
            a2 = fmaf(__shfl(x2, base + i), W2[i * 32], a2);
            a3 = fmaf(__shfl(x3, base + i), W3[i * 32], a3);
        }
        atomicAdd(&xout[d0 * H + o], a0 * i0);   // wave-contiguous rows
        atomicAdd(&xout[d1 * H + o], a1 * i1);
        atomicAdd(&xout[d2 * H + o], a2 * i2);
        atomicAdd(&xout[d3 * H + o], a3 * i3);
    } else if (b < EBLK + SBLK) {           // self: out[n] += x[n]@root + b
        int t0 = (b - EBLK) * 256 + threadIdx.x;
        int o = t0 & 31;
#pragma unroll
        for (int k = 0; k < 2; ++k) {
            int t2 = t0 + k * 262144;
            float xv = xin[t2];
            if (relu_in) xv = fmaxf(xv, 0.f);
            float acc = Bl[o];
#pragma unroll
            for (int i = 0; i < 32; ++i)
                acc = fmaf(__shfl(xv, base + i), Rl[i * 32 + o], acc);
            atomicAdd(&xout[t2], acc);
        }
    } else if (zb) {                        // zero next accumulator
        int t0 = (b - EBLK - SBLK) * 256 + threadIdx.x;
        zb[t0] = 0.f;
        zb[t0 + 262144] = 0.f;
    }
}

// ---- readout: one thread per output element (B x 128) ----
__global__ void k_final(const float* __restrict__ x, const int* __restrict__ metal_idx,
                        const int* __restrict__ loop_edge, const int* __restrict__ loop_pair,
                        const float* __restrict__ f_w, const float* __restrict__ f_b,
                        float* __restrict__ out) {
    int tid = blockIdx.x * blockDim.x + threadIdx.x;
    if (tid >= BB * 128) return;
    int b = tid >> 7, j = tid & 127;
    int mg = metal_idx[b] + b * NPERB;
    const float* __restrict__ xm = x + mg * H;
    int p0, p1;
    if (j < 64) {
        p0 = loop_edge[(b * 64 + j) * 2];
        p1 = loop_edge[(b * 64 + j) * 2 + 1];
    } else {
        int j2 = j - 64;
        p0 = loop_pair[(b * 64 + j2) * 2];
        p1 = loop_pair[(b * 64 + j2) * 2 + 1];
    }
    const float* __restrict__ xs = x + (b * NPERB + p0) * H;
    const float* __restrict__ xt = x + (b * NPERB + p1) * H;
    float fh = f_b[0];
    float pp = 0.f;
#pragma unroll
    for (int h = 0; h < H; ++h) {
        float m = xm[h];
        fh = fmaf(m, f_w[h], fh);
        pp += m * (xs[h] + xt[h]) - xs[h] * xt[h];
    }
    out[tid] = (j < 64) ? (pp - fh) : (-pp);
}

extern "C" void kernel_launch(void* const* d_in, const int* in_sizes, int n_in,
                              void* d_out, int out_size, void* d_ws, size_t ws_size,
                              hipStream_t stream) {
    const int*   x_nodes    = (const int*)d_in[0];
    const int*   edge_index = (const int*)d_in[1];
    const int*   edge_attr  = (const int*)d_in[2];
    const int*   metal_idx  = (const int*)d_in[3];
    const int*   loop_edge  = (const int*)d_in[4];
    const int*   loop_pair  = (const int*)d_in[5];
    const float* node_emb   = (const float*)d_in[6];
    const float* edge_emb   = (const float*)d_in[7];
    const float* lin_w      = (const float*)d_in[8];
    const float* lin_b      = (const float*)d_in[9];
    const float* root_w     = (const float*)d_in[10];
    const float* conv_b     = (const float*)d_in[11];
    const float* f_w        = (const float*)d_in[12];
    const float* f_b        = (const float*)d_in[13];
    float* out = (float*)d_out;

    float* ws   = (float*)d_ws;
    float* buf0 = ws;                          // 512K floats
    float* buf1 = buf0 + NN * H;               // 512K
    float* buf2 = buf1 + NN * H;               // 512K
    float* degf = buf2 + NN * H;               // NN       (zeroed)
    int*   tcount  = (int*)(degf + NN);        // 16       (zeroed)
    int*   gcursor = tcount + 16;              // 16       (zeroed)
    unsigned int* blist = (unsigned int*)(gcursor + 16);   // NE
    float* Wt   = (float*)(blist + NE);        // 4*16*1024

    hipMemsetAsync(degf, 0, (NN + 32) * sizeof(float), stream);

    k_prep1<<<1536, 256, 0, stream>>>(x_nodes, edge_index, edge_attr, node_emb,
                                      edge_emb, lin_w, lin_b, buf0, Wt, degf, tcount, buf1);
    k_prep2<<<1, 64, 0, stream>>>(tcount, gcursor);
    k_prep3<<<256, 256, 0, stream>>>(edge_index, edge_attr, gcursor, blist);

    // rotation: buf0->buf1 (zero buf2), buf1->buf2 (zero buf0),
    //           buf2->buf0 (zero buf1), buf0->buf1 (no zero). final reads buf1.
    k_phase<<<4096, 256, 0, stream>>>(buf0, buf1, buf2, blist, degf,
                                      Wt + 0 * 16384, root_w + 0 * 1024, conv_b + 0 * H, 0);
    k_phase<<<4096, 256, 0, stream>>>(buf1, buf2, buf0, blist, degf,
                                      Wt + 1 * 16384, root_w + 1 * 1024, conv_b + 1 * H, 1);
    k_phase<<<4096, 256, 0, stream>>>(buf2, buf0, buf1, blist, degf,
                                      Wt + 2 * 16384, root_w + 2 * 1024, conv_b + 2 * H, 1);
    k_phase<<<3072, 256, 0, stream>>>(buf0, buf1, (float*)0, blist, degf,
                                      Wt + 3 * 16384, root_w + 3 * 1024, conv_b + 3 * H, 1);

    k_final<<<16, 256, 0, stream>>>(buf1, metal_idx, loop_edge, loop_pair, f_w, f_b, out);
}